// Round 3
// baseline (865.208 us; speedup 1.0000x reference)
//
#include <hip/hip_runtime.h>

#define TPB 1024

// LDS layout (bytes):
//   Ksh f16 row-major 256x256   [0, 131072)   (staging + one-time extraction only)
//   u0  f16[256]                [131072, 131584)   u ping-pong buffer 0
//   u1  f16[256]                [131584, 132096)   u ping-pong buffer 1
//   vh  f16[256]                [132096, 132608)
//   a_sh f32[256]               [132608, 133632)
//   b_sh f32[256]               [133632, 134656)
//   scr  f32[32]                [134656, 134784)
//   aflag int[8]                [134784, 134816)   pass-A completion counters (per 32-row chunk)
//   bflag int[8]                [134816, 134848)   pass-B completion counters
#define SMEM_BYTES 134848

typedef _Float16 f16x8 __attribute__((ext_vector_type(8)));
typedef _Float16 f16x4 __attribute__((ext_vector_type(4)));
typedef _Float16 h2    __attribute__((ext_vector_type(2)));
typedef float    f32x4 __attribute__((ext_vector_type(4)));

union HU { unsigned u; h2 h; };

// Select element (c & 3) of a f32x4 accumulator with 2 cndmasks.
static __device__ __forceinline__ float sel4(f32x4 a, int c) {
    float x01 = (c & 1) ? a[1] : a[0];
    float x23 = (c & 1) ? a[3] : a[2];
    return (c & 2) ? x23 : x01;
}

// Spin until flags[0..3] all reach lim. Relaxed loads in the loop (issue 4
// ds_reads back-to-back, single wait for the compare), one acquire fence on
// exit so subsequent ds_reads of the gated data cannot be hoisted above.
// BOUNDED: a correct run never comes close to SPIN_MAX (legit inter-wave skew
// is O(1e3) cycles; 4096 polls is ~5e5 cycles of margin). The bound converts
// any latent sync bug from a GPU hang (container death, no diagnostics) into
// a bounded-runtime wrong answer (absmax + counters) — strictly better signal.
#define SPIN_MAX 4096
static __device__ __forceinline__ void wait4(const int* f, int lim) {
    for (int k = 0; k < SPIN_MAX; ++k) {
        int f0 = __hip_atomic_load(&f[0], __ATOMIC_RELAXED, __HIP_MEMORY_SCOPE_WORKGROUP);
        int f1 = __hip_atomic_load(&f[1], __ATOMIC_RELAXED, __HIP_MEMORY_SCOPE_WORKGROUP);
        int f2 = __hip_atomic_load(&f[2], __ATOMIC_RELAXED, __HIP_MEMORY_SCOPE_WORKGROUP);
        int f3 = __hip_atomic_load(&f[3], __ATOMIC_RELAXED, __HIP_MEMORY_SCOPE_WORKGROUP);
        if (f0 >= lim && f1 >= lim && f2 >= lim && f3 >= lim) break;
    }
    __builtin_amdgcn_fence(__ATOMIC_ACQUIRE, "workgroup");
}

// Release-signal: order prior LDS ops before the counter bump.
// Must be called under "if (lane == 0)".
static __device__ __forceinline__ void signal(int* f) {
    __builtin_amdgcn_fence(__ATOMIC_RELEASE, "workgroup");
    __hip_atomic_fetch_add(f, 1, __ATOMIC_RELAXED, __HIP_MEMORY_SCOPE_WORKGROUP);
}

__global__ __launch_bounds__(TPB, 4) void sinkhorn_kernel(
    const float* __restrict__ cost,
    const float* __restrict__ mass_pred,
    const float* __restrict__ mass_target,
    float* __restrict__ out)
{
    extern __shared__ char smem[];
    _Float16* Ksh = (_Float16*)smem;                 // 256 x 256, row-major
    _Float16* u0  = (_Float16*)(smem + 131072);
    _Float16* u1  = (_Float16*)(smem + 131584);
    _Float16* vh  = (_Float16*)(smem + 132096);
    float* a_sh   = (float*)(smem + 132608);
    float* b_sh   = (float*)(smem + 133632);
    float* scr    = (float*)(smem + 134656);
    int*   aflag  = (int*)(smem + 134784);
    int*   bflag  = (int*)(smem + 134816);

    const int t    = threadIdx.x;
    const int bat  = blockIdx.x;
    const int l    = t & 63;
    const int w    = t >> 6;        // wave 0..15; wave tile = rows [16w, 16w+16)
    const int quad = (l >> 4) & 3;  // MFMA quad group
    const int col  = l & 15;        // MFMA column lane
    // lane (quad, col<4) owns output element row 16w + 4*quad + col
    const int own  = 16 * w + 4 * quad + (col & 3);
    const int pair = w >> 1;        // 32-row chunk this wave contributes to

    //---------------- Phase 0: normalize masses, init u, init flags -------
    if (t < 8) { aflag[t] = 0; bflag[t] = 0; }
    float vmp = 0.f, vmt = 0.f;
    if (t < 256) {
        vmp = mass_pred [bat * 256 + t];
        vmt = mass_target[bat * 256 + t];
    }
    float s1 = vmp, s2 = vmt;
#pragma unroll
    for (int o = 32; o > 0; o >>= 1) {
        s1 += __shfl_xor(s1, o);
        s2 += __shfl_xor(s2, o);
    }
    if (t < 256 && l == 0) { scr[w] = s1; scr[8 + w] = s2; }
    if (t < 256) u0[t] = (_Float16)1.0f;
    __syncthreads();
    if (t == 0) {
        float ta = 0.f, tb = 0.f;
#pragma unroll
        for (int ww = 0; ww < 4; ++ww) { ta += scr[ww]; tb += scr[8 + ww]; }
        scr[16] = ta + 1e-8f;
        scr[17] = tb + 1e-8f;
    }
    __syncthreads();
    if (t < 256) {
        a_sh[t] = vmp / scr[16];
        b_sh[t] = vmt / scr[17];
    }

    //---------------- Phase 1: K = exp(-C/eps) -> f16 row-major LDS ------
    {
        const float4* C4 = (const float4*)(cost + (size_t)bat * 65536);
#pragma unroll 4
        for (int i = 0; i < 16; ++i) {
            int idx = i * TPB + t;       // float4 index: row = idx>>6, col4 = idx&63
            float4 c = C4[idx];
            int n = idx >> 6, col4 = idx & 63;
            HU p01, p23;
            p01.h = (h2){(_Float16)__expf(c.x * -10.0f), (_Float16)__expf(c.y * -10.0f)};
            p23.h = (h2){(_Float16)__expf(c.z * -10.0f), (_Float16)__expf(c.w * -10.0f)};
            *(uint2*)((char*)Ksh + n * 512 + col4 * 8) = make_uint2(p01.u, p23.u);
        }
    }
    __syncthreads();   // Ksh ready; also publishes u0/a_sh/b_sh/flags

    //---------------- One-time fragment extraction ------------------------
    // Pass-A (K^T u): afrag[c][j] = K[32c+quad*8+j][16w+col]  (A-layout of K^T)
    f16x8 afrag[8];
#pragma unroll
    for (int c = 0; c < 8; ++c) {
#pragma unroll
        for (int j = 0; j < 8; ++j)
            afrag[c][j] = Ksh[(32 * c + quad * 8 + j) * 256 + 16 * w + col];
    }
    // Pass-B (K v): bfrag[c][j] = K[16w+col][32c+quad*8+j] (row-contig b128)
    f16x8 bfrag[8];
#pragma unroll
    for (int c = 0; c < 8; ++c)
        bfrag[c] = *(const f16x8*)&Ksh[(16 * w + col) * 256 + 32 * c + quad * 8];

    // Loop-invariant scalars (a_sh/b_sh never change after phase 0)
    const float bb = b_sh[own];
    const float aa = a_sh[own];

    //---------------- Phase 2: 100 Sinkhorn iterations --------------------
    // Barrier-free: per-chunk epoch counters gate the two all-to-all handoffs.
    // u is double-buffered (read ucur, write unxt) so pass-B writes can never
    // race pass-A reads of the live buffer. vh stays single-buffered: before
    // any wave writes vh in pass A of iter t it has polled ALL 8 bflags >= 2t,
    // which transitively proves every wave finished pass B of t-1 (and thus
    // all vh reads of iter t-1).
    _Float16* ucur = u0;
    _Float16* unxt = u1;
    for (int it = 0; it < 100; ++it) {
        const int limB = 2 * it;        // B(it-1) complete per chunk
        const int limA = 2 * it + 2;    // A(it)   complete per chunk
        // ---- Pass A: Ktu = K^T u via MFMA (B = u broadcast across columns)
        {
            f32x4 c0 = {0.f, 0.f, 0.f, 0.f}, c1 = c0, c2 = c0, c3 = c0;
            // stage 0: chunks 0..3 (needs u[0:128) = pass-B output of waves 0..7)
            wait4(&bflag[0], limB);
            f16x8 uf0 = *(const f16x8*)&ucur[quad * 8];
            f16x8 uf1 = *(const f16x8*)&ucur[32 + quad * 8];
            f16x8 uf2 = *(const f16x8*)&ucur[64 + quad * 8];
            f16x8 uf3 = *(const f16x8*)&ucur[96 + quad * 8];
            c0 = __builtin_amdgcn_mfma_f32_16x16x32_f16(afrag[0], uf0, c0, 0, 0, 0);
            c1 = __builtin_amdgcn_mfma_f32_16x16x32_f16(afrag[1], uf1, c1, 0, 0, 0);
            c2 = __builtin_amdgcn_mfma_f32_16x16x32_f16(afrag[2], uf2, c2, 0, 0, 0);
            c3 = __builtin_amdgcn_mfma_f32_16x16x32_f16(afrag[3], uf3, c3, 0, 0, 0);
            // stage 1: chunks 4..7
            wait4(&bflag[4], limB);
            f16x8 uf4 = *(const f16x8*)&ucur[128 + quad * 8];
            f16x8 uf5 = *(const f16x8*)&ucur[160 + quad * 8];
            f16x8 uf6 = *(const f16x8*)&ucur[192 + quad * 8];
            f16x8 uf7 = *(const f16x8*)&ucur[224 + quad * 8];
            c0 = __builtin_amdgcn_mfma_f32_16x16x32_f16(afrag[4], uf4, c0, 0, 0, 0);
            c1 = __builtin_amdgcn_mfma_f32_16x16x32_f16(afrag[5], uf5, c1, 0, 0, 0);
            c2 = __builtin_amdgcn_mfma_f32_16x16x32_f16(afrag[6], uf6, c2, 0, 0, 0);
            c3 = __builtin_amdgcn_mfma_f32_16x16x32_f16(afrag[7], uf7, c3, 0, 0, 0);
            float kt = (sel4(c0, col) + sel4(c1, col)) +
                       (sel4(c2, col) + sel4(c3, col));
            float vvv = bb * __builtin_amdgcn_rcpf(kt + 1e-8f);
            if (col < 4) vh[own] = (_Float16)vvv;
            if (l == 0) signal(&aflag[pair]);
        }

        // ---- Pass B: Kv = K v via MFMA (B = v broadcast across columns)
        {
            f32x4 c0 = {0.f, 0.f, 0.f, 0.f}, c1 = c0, c2 = c0, c3 = c0;
            // stage 0: chunks 0..3 (needs v[0:128) = pass-A output of waves 0..7)
            wait4(&aflag[0], limA);
            f16x8 vf0 = *(const f16x8*)&vh[quad * 8];
            f16x8 vf1 = *(const f16x8*)&vh[32 + quad * 8];
            f16x8 vf2 = *(const f16x8*)&vh[64 + quad * 8];
            f16x8 vf3 = *(const f16x8*)&vh[96 + quad * 8];
            c0 = __builtin_amdgcn_mfma_f32_16x16x32_f16(bfrag[0], vf0, c0, 0, 0, 0);
            c1 = __builtin_amdgcn_mfma_f32_16x16x32_f16(bfrag[1], vf1, c1, 0, 0, 0);
            c2 = __builtin_amdgcn_mfma_f32_16x16x32_f16(bfrag[2], vf2, c2, 0, 0, 0);
            c3 = __builtin_amdgcn_mfma_f32_16x16x32_f16(bfrag[3], vf3, c3, 0, 0, 0);
            // stage 1: chunks 4..7
            wait4(&aflag[4], limA);
            f16x8 vf4 = *(const f16x8*)&vh[128 + quad * 8];
            f16x8 vf5 = *(const f16x8*)&vh[160 + quad * 8];
            f16x8 vf6 = *(const f16x8*)&vh[192 + quad * 8];
            f16x8 vf7 = *(const f16x8*)&vh[224 + quad * 8];
            c0 = __builtin_amdgcn_mfma_f32_16x16x32_f16(bfrag[4], vf4, c0, 0, 0, 0);
            c1 = __builtin_amdgcn_mfma_f32_16x16x32_f16(bfrag[5], vf5, c1, 0, 0, 0);
            c2 = __builtin_amdgcn_mfma_f32_16x16x32_f16(bfrag[6], vf6, c2, 0, 0, 0);
            c3 = __builtin_amdgcn_mfma_f32_16x16x32_f16(bfrag[7], vf7, c3, 0, 0, 0);
            float kv = (sel4(c0, col) + sel4(c1, col)) +
                       (sel4(c2, col) + sel4(c3, col));
            float uuu = aa * __builtin_amdgcn_rcpf(kv + 1e-8f);
            if (col < 4) unxt[own] = (_Float16)uuu;
            if (l == 0) signal(&bflag[pair]);
        }
        // swap u ping-pong
        _Float16* tmp = ucur; ucur = unxt; unxt = tmp;
    }
    __syncthreads();   // all waves done; vh = final v, ucur = final u

    //---------------- Phase 3: cost = sum u K v C, C = -eps log K ---------
    // bfrag[c][j] = K[n][k], n = 16w+col, k = 32c+quad*8+j. Each (n,k) covered
    // exactly once across lanes/waves.
    float s = 0.f;
    {
        float uN = (float)ucur[16 * w + col];
#pragma unroll
        for (int c = 0; c < 8; ++c) {
            f16x8 vf = *(const f16x8*)&vh[32 * c + quad * 8];
#pragma unroll
            for (int j = 0; j < 8; ++j) {
                float kv = (float)bfrag[c][j];
                float cv = -0.1f * __logf(kv);
                s = fmaf(kv * cv, (float)vf[j], s);
            }
        }
        s *= uN;
    }
#pragma unroll
    for (int o = 32; o > 0; o >>= 1) s += __shfl_xor(s, o);
    if (l == 0) scr[w] = s;
    __syncthreads();
    if (t == 0) {
        float tot = 0.f;
#pragma unroll
        for (int ww = 0; ww < 16; ++ww) tot += scr[ww];
        atomicAdd(out, tot * (1.0f / 1024.0f));
    }
}

extern "C" void kernel_launch(void* const* d_in, const int* in_sizes, int n_in,
                              void* d_out, int out_size, void* d_ws, size_t ws_size,
                              hipStream_t stream) {
    const float* cost = (const float*)d_in[0];
    const float* mp   = (const float*)d_in[1];
    const float* mt   = (const float*)d_in[2];
    float* out = (float*)d_out;

    // out is re-poisoned to 0xAA before every timed launch -> zero it
    hipMemsetAsync(out, 0, sizeof(float), stream);

    // >64KB dynamic LDS: opt in (gfx950 has 160KB/CU)
    hipFuncSetAttribute((const void*)sinkhorn_kernel,
                        hipFuncAttributeMaxDynamicSharedMemorySize, SMEM_BYTES);

    sinkhorn_kernel<<<1024, TPB, SMEM_BYTES, stream>>>(cost, mp, mt, out);
}

// Round 4
// 647.130 us; speedup vs baseline: 1.3370x; 1.3370x over previous
//
#include <hip/hip_runtime.h>

#define TPB 1024

// LDS layout (bytes):
//   Ksh f16 row-major 256x256   [0, 131072)   (staging + one-time extraction only)
//   u0  f16[256]                [131072, 131584)   u ping-pong buffer 0
//   u1  f16[256]                [131584, 132096)   u ping-pong buffer 1
//   vh  f16[256]                [132096, 132608)
//   a_sh f32[256]               [132608, 133632)
//   b_sh f32[256]               [133632, 134656)
//   scr  f32[32]                [134656, 134784)
#define SMEM_BYTES 134784

typedef _Float16 f16x8 __attribute__((ext_vector_type(8)));
typedef _Float16 h2    __attribute__((ext_vector_type(2)));
typedef float    f32x4 __attribute__((ext_vector_type(4)));

union HU { unsigned u; h2 h; };

// One matvec pass: r = sum_k frag-matrix * vec, with the VECTOR in the MFMA
// A-slot (broadcast over rows) and the K-FRAGMENT in the B-slot. Output
// D[m][n] is then independent of m: every acc reg of lane (quad,col) holds
// the result for element (tile_base + col). No sel4 extraction needed.
// Accumulation order (chunk c into acc c&3, chained pairs) matches the
// original kernel bit-for-bit.
static __device__ __forceinline__ float mv16(const f16x8 (&frag)[8],
                                             const _Float16* __restrict__ vec,
                                             int quad) {
    f16x8 x0 = *(const f16x8*)&vec[      quad * 8];
    f16x8 x1 = *(const f16x8*)&vec[ 32 + quad * 8];
    f16x8 x2 = *(const f16x8*)&vec[ 64 + quad * 8];
    f16x8 x3 = *(const f16x8*)&vec[ 96 + quad * 8];
    f16x8 x4 = *(const f16x8*)&vec[128 + quad * 8];
    f16x8 x5 = *(const f16x8*)&vec[160 + quad * 8];
    f16x8 x6 = *(const f16x8*)&vec[192 + quad * 8];
    f16x8 x7 = *(const f16x8*)&vec[224 + quad * 8];
    f32x4 c0 = {0.f, 0.f, 0.f, 0.f}, c1 = c0, c2 = c0, c3 = c0;
    c0 = __builtin_amdgcn_mfma_f32_16x16x32_f16(x0, frag[0], c0, 0, 0, 0);
    c1 = __builtin_amdgcn_mfma_f32_16x16x32_f16(x1, frag[1], c1, 0, 0, 0);
    c2 = __builtin_amdgcn_mfma_f32_16x16x32_f16(x2, frag[2], c2, 0, 0, 0);
    c3 = __builtin_amdgcn_mfma_f32_16x16x32_f16(x3, frag[3], c3, 0, 0, 0);
    c0 = __builtin_amdgcn_mfma_f32_16x16x32_f16(x4, frag[4], c0, 0, 0, 0);
    c1 = __builtin_amdgcn_mfma_f32_16x16x32_f16(x5, frag[5], c1, 0, 0, 0);
    c2 = __builtin_amdgcn_mfma_f32_16x16x32_f16(x6, frag[6], c2, 0, 0, 0);
    c3 = __builtin_amdgcn_mfma_f32_16x16x32_f16(x7, frag[7], c3, 0, 0, 0);
    return (c0[0] + c1[0]) + (c2[0] + c3[0]);
}

__global__ __launch_bounds__(TPB, 4) void sinkhorn_kernel(
    const float* __restrict__ cost,
    const float* __restrict__ mass_pred,
    const float* __restrict__ mass_target,
    float* __restrict__ out)
{
    extern __shared__ char smem[];
    _Float16* Ksh = (_Float16*)smem;                 // 256 x 256, row-major
    _Float16* u0  = (_Float16*)(smem + 131072);
    _Float16* u1  = (_Float16*)(smem + 131584);
    _Float16* vh  = (_Float16*)(smem + 132096);
    float* a_sh   = (float*)(smem + 132608);
    float* b_sh   = (float*)(smem + 133632);
    float* scr    = (float*)(smem + 134656);

    const int t    = threadIdx.x;
    const int bat  = blockIdx.x;
    const int l    = t & 63;
    const int w    = t >> 6;        // wave 0..15; wave tile = rows [16w, 16w+16)
    const int quad = (l >> 4) & 3;  // MFMA quad group
    const int col  = l & 15;        // MFMA column lane
    // with vector-in-A-slot MFMA, lane (quad,col) produces element 16w+col
    const int oc   = 16 * w + col;

    //---------------- Phase 0: normalize masses, init u ----------------
    float vmp = 0.f, vmt = 0.f;
    if (t < 256) {
        vmp = mass_pred [bat * 256 + t];
        vmt = mass_target[bat * 256 + t];
    }
    float s1 = vmp, s2 = vmt;
#pragma unroll
    for (int o = 32; o > 0; o >>= 1) {
        s1 += __shfl_xor(s1, o);
        s2 += __shfl_xor(s2, o);
    }
    if (t < 256 && l == 0) { scr[w] = s1; scr[8 + w] = s2; }
    if (t < 256) u0[t] = (_Float16)1.0f;
    __syncthreads();
    if (t == 0) {
        float ta = 0.f, tb = 0.f;
#pragma unroll
        for (int ww = 0; ww < 4; ++ww) { ta += scr[ww]; tb += scr[8 + ww]; }
        scr[16] = ta + 1e-8f;
        scr[17] = tb + 1e-8f;
    }
    __syncthreads();
    if (t < 256) {
        a_sh[t] = vmp / scr[16];
        b_sh[t] = vmt / scr[17];
    }

    //---------------- Phase 1: K = exp(-C/eps) -> f16 row-major LDS ------
    {
        const float4* C4 = (const float4*)(cost + (size_t)bat * 65536);
#pragma unroll 4
        for (int i = 0; i < 16; ++i) {
            int idx = i * TPB + t;       // float4 index: row = idx>>6, col4 = idx&63
            float4 c = C4[idx];
            int n = idx >> 6, col4 = idx & 63;
            HU p01, p23;
            p01.h = (h2){(_Float16)__expf(c.x * -10.0f), (_Float16)__expf(c.y * -10.0f)};
            p23.h = (h2){(_Float16)__expf(c.z * -10.0f), (_Float16)__expf(c.w * -10.0f)};
            *(uint2*)((char*)Ksh + n * 512 + col4 * 8) = make_uint2(p01.u, p23.u);
        }
    }
    __syncthreads();   // Ksh ready; also publishes u0/a_sh/b_sh

    //---------------- One-time fragment extraction ------------------------
    // afrag[c][j] = K[32c+quad*8+j][16w+col]  (column-owned; B-slot for K^T u)
    f16x8 afrag[8];
#pragma unroll
    for (int c = 0; c < 8; ++c) {
#pragma unroll
        for (int j = 0; j < 8; ++j)
            afrag[c][j] = Ksh[(32 * c + quad * 8 + j) * 256 + 16 * w + col];
    }
    // bfrag[c][j] = K[16w+col][32c+quad*8+j]  (row-owned; B-slot for K v)
    f16x8 bfrag[8];
#pragma unroll
    for (int c = 0; c < 8; ++c)
        bfrag[c] = *(const f16x8*)&Ksh[(16 * w + col) * 256 + 32 * c + quad * 8];

    // Loop-invariant scalars for the tail (element oc of b / a)
    const float bb = b_sh[oc];
    const float aa = a_sh[oc];

    //---------------- Phase 2: 100 Sinkhorn iterations --------------------
    // Unrolled by 2 so the u ping-pong pointers are compile-time constants.
    // Pass A: v = b / (K^T u);  Pass B: u = a / (K v).
    for (int ip = 0; ip < 50; ++ip) {
        {   // A: u0 -> vh
            float kt = mv16(afrag, u0, quad);
            float vvv = bb * __builtin_amdgcn_rcpf(kt + 1e-8f);
            if (l < 16) vh[16 * w + l] = (_Float16)vvv;
        }
        __syncthreads();
        {   // B: vh -> u1
            float kv = mv16(bfrag, vh, quad);
            float uuu = aa * __builtin_amdgcn_rcpf(kv + 1e-8f);
            if (l < 16) u1[16 * w + l] = (_Float16)uuu;
        }
        __syncthreads();
        {   // A: u1 -> vh
            float kt = mv16(afrag, u1, quad);
            float vvv = bb * __builtin_amdgcn_rcpf(kt + 1e-8f);
            if (l < 16) vh[16 * w + l] = (_Float16)vvv;
        }
        __syncthreads();
        {   // B: vh -> u0
            float kv = mv16(bfrag, vh, quad);
            float uuu = aa * __builtin_amdgcn_rcpf(kv + 1e-8f);
            if (l < 16) u0[16 * w + l] = (_Float16)uuu;
        }
        __syncthreads();
    }
    // final u is in u0, final v in vh

    //---------------- Phase 3: cost = sum u K v C, C = -eps log K ---------
    // bfrag[c][j] = K[n][k], n = 16w+col, k = 32c+quad*8+j. Each (n,k) covered
    // exactly once across lanes/waves.
    float s = 0.f;
    {
        float uN = (float)u0[16 * w + col];
#pragma unroll
        for (int c = 0; c < 8; ++c) {
            f16x8 vf = *(const f16x8*)&vh[32 * c + quad * 8];
#pragma unroll
            for (int j = 0; j < 8; ++j) {
                float kv = (float)bfrag[c][j];
                float cv = -0.1f * __logf(kv);
                s = fmaf(kv * cv, (float)vf[j], s);
            }
        }
        s *= uN;
    }
#pragma unroll
    for (int o = 32; o > 0; o >>= 1) s += __shfl_xor(s, o);
    if (l == 0) scr[w] = s;
    __syncthreads();
    if (t == 0) {
        float tot = 0.f;
#pragma unroll
        for (int ww = 0; ww < 16; ++ww) tot += scr[ww];
        atomicAdd(out, tot * (1.0f / 1024.0f));
    }
}

extern "C" void kernel_launch(void* const* d_in, const int* in_sizes, int n_in,
                              void* d_out, int out_size, void* d_ws, size_t ws_size,
                              hipStream_t stream) {
    const float* cost = (const float*)d_in[0];
    const float* mp   = (const float*)d_in[1];
    const float* mt   = (const float*)d_in[2];
    float* out = (float*)d_out;

    // out is re-poisoned to 0xAA before every timed launch -> zero it
    hipMemsetAsync(out, 0, sizeof(float), stream);

    // >64KB dynamic LDS: opt in (gfx950 has 160KB/CU)
    hipFuncSetAttribute((const void*)sinkhorn_kernel,
                        hipFuncAttributeMaxDynamicSharedMemorySize, SMEM_BYTES);

    sinkhorn_kernel<<<1024, TPB, SMEM_BYTES, stream>>>(cost, mp, mt, out);
}